// Round 1
// baseline (2757.976 us; speedup 1.0000x reference)
//
#include <hip/hip_runtime.h>
#include <hip/hip_bf16.h>

// Problem dims
#define BB  2048
#define TT  128
#define DD  128
#define HH1 128
#define GG1 512   // 4*H1
#define HH2 64
#define GG2 256   // 4*H2
#define OO  64

// ws layout (float offsets)
#define WS_W1T  0                      // [DD][GG1]  w_ih1 transposed
#define WS_WH1T 65536                  // [HH1][GG1] w_hh1 transposed
#define WS_W2T  131072                 // [HH1][GG2] w_ih2 transposed
#define WS_WH2T 163840                 // [HH2][GG2] w_hh2 transposed
#define WS_WDT  180224                 // [HH2][OO]  w_dense transposed
#define WS_B1   184320                 // [GG1] b_ih1+b_hh1
#define WS_B2   184832                 // [GG2] b_ih2+b_hh2
#define WS_BD   185088                 // [OO]
#define WS_H1S  185152                 // [BB][TT][HH1] fp32 layer-1 hidden seq
#define WS_XG1  (185152 + 33554432)    // bf16 region: [BB*TT][GG1] precomputed gates
// total ws = 4*WS_XG1 + 2*BB*TT*GG1 = ~403 MB

__device__ __forceinline__ float sigm(float x) { return 1.0f / (1.0f + __expf(-x)); }
__device__ __forceinline__ float tanh_fast(float x) { return 1.0f - 2.0f / (1.0f + __expf(2.0f * x)); }

// ---------------- prep: transpose weights, combine biases ----------------
__global__ void k_prep(const float* __restrict__ w_ih1, const float* __restrict__ w_hh1,
                       const float* __restrict__ b_ih1, const float* __restrict__ b_hh1,
                       const float* __restrict__ w_ih2, const float* __restrict__ w_hh2,
                       const float* __restrict__ b_ih2, const float* __restrict__ b_hh2,
                       const float* __restrict__ w_dense, const float* __restrict__ b_dense,
                       float* __restrict__ ws) {
  int idx = blockIdx.x * blockDim.x + threadIdx.x;
  int stride = gridDim.x * blockDim.x;
  for (int i = idx; i < DD * GG1; i += stride) {   // W1T[k][g] = w_ih1[g][k]
    int k = i >> 9, g = i & 511;
    ws[WS_W1T + i] = w_ih1[g * DD + k];
  }
  for (int i = idx; i < HH1 * GG1; i += stride) {
    int k = i >> 9, g = i & 511;
    ws[WS_WH1T + i] = w_hh1[g * HH1 + k];
  }
  for (int i = idx; i < HH1 * GG2; i += stride) {
    int k = i >> 8, g = i & 255;
    ws[WS_W2T + i] = w_ih2[g * HH1 + k];
  }
  for (int i = idx; i < HH2 * GG2; i += stride) {
    int k = i >> 8, g = i & 255;
    ws[WS_WH2T + i] = w_hh2[g * HH2 + k];
  }
  for (int i = idx; i < HH2 * OO; i += stride) {
    int k = i >> 6, o = i & 63;
    ws[WS_WDT + i] = w_dense[o * HH2 + k];
  }
  for (int i = idx; i < GG1; i += stride) ws[WS_B1 + i] = b_ih1[i] + b_hh1[i];
  for (int i = idx; i < GG2; i += stride) ws[WS_B2 + i] = b_ih2[i] + b_hh2[i];
  for (int i = idx; i < OO;  i += stride) ws[WS_BD + i] = b_dense[i];
}

// ---------------- gemm1: xg1[m][g] = sum_k x[m][k]*W1T[k][g] + B1[g] ----------------
#define MT1 32
__global__ __launch_bounds__(512) void k_gemm1(const float* __restrict__ x,
                                               const float* __restrict__ ws,
                                               __hip_bfloat16* __restrict__ xg1) {
  __shared__ float xs[MT1][DD];  // 16 KB
  const float* W1T = ws + WS_W1T;
  const size_t m0 = (size_t)blockIdx.x * MT1;
  {
    const float4* src = (const float4*)(x + m0 * DD);
    float4* dst = (float4*)&xs[0][0];
    dst[threadIdx.x] = src[threadIdx.x];
    dst[threadIdx.x + 512] = src[threadIdx.x + 512];
  }
  __syncthreads();
  const int g = threadIdx.x;
  float acc[MT1];
#pragma unroll
  for (int r = 0; r < MT1; ++r) acc[r] = 0.f;
  for (int k = 0; k < DD; k += 4) {
    float w0 = W1T[(k + 0) * GG1 + g];
    float w1 = W1T[(k + 1) * GG1 + g];
    float w2 = W1T[(k + 2) * GG1 + g];
    float w3 = W1T[(k + 3) * GG1 + g];
#pragma unroll
    for (int r = 0; r < MT1; ++r) {
      float4 xv = *(const float4*)&xs[r][k];
      acc[r] = fmaf(xv.x, w0, acc[r]);
      acc[r] = fmaf(xv.y, w1, acc[r]);
      acc[r] = fmaf(xv.z, w2, acc[r]);
      acc[r] = fmaf(xv.w, w3, acc[r]);
    }
  }
  const float b = ws[WS_B1 + g];
#pragma unroll
  for (int r = 0; r < MT1; ++r)
    xg1[(m0 + r) * GG1 + g] = __float2bfloat16(acc[r] + b);
}

// ---------------- rec1: layer-1 recurrence, 8 batch rows per block ----------------
__global__ __launch_bounds__(512) void k_rec1(const __hip_bfloat16* __restrict__ xg1,
                                              const float* __restrict__ ws,
                                              float* __restrict__ h1s) {
  __shared__ float hs[8][HH1];    // 4 KB  hidden state
  __shared__ float gsh[8][GG1];   // 16 KB activated gates
  const float* WhT = ws + WS_WH1T;
  const int r0 = blockIdx.x * 8;
  const int g = threadIdx.x;               // gate column 0..511
  const int j = threadIdx.x & 127;         // cell col
  const int rA = threadIdx.x >> 7;         // cell rows rA, rA+4
  const int rB = rA + 4;
  float cA = 0.f, cB = 0.f;
  ((float*)hs)[threadIdx.x] = 0.f;
  ((float*)hs)[threadIdx.x + 512] = 0.f;
  __syncthreads();
  const bool isg = (g >= 256) && (g < 384);

  for (int t = 0; t < TT; ++t) {
    float acc[8];
    const __hip_bfloat16* xgp = xg1 + ((size_t)r0 * TT + t) * GG1 + g;
#pragma unroll
    for (int r = 0; r < 8; ++r) acc[r] = __bfloat162float(xgp[(size_t)r * TT * GG1]);

    for (int k = 0; k < HH1; k += 4) {
      float w0 = WhT[(k + 0) * GG1 + g];
      float w1 = WhT[(k + 1) * GG1 + g];
      float w2 = WhT[(k + 2) * GG1 + g];
      float w3 = WhT[(k + 3) * GG1 + g];
#pragma unroll
      for (int r = 0; r < 8; ++r) {
        float4 hv = *(const float4*)&hs[r][k];
        acc[r] = fmaf(hv.x, w0, acc[r]);
        acc[r] = fmaf(hv.y, w1, acc[r]);
        acc[r] = fmaf(hv.z, w2, acc[r]);
        acc[r] = fmaf(hv.w, w3, acc[r]);
      }
    }
    if (isg) {
#pragma unroll
      for (int r = 0; r < 8; ++r) gsh[r][g] = tanh_fast(acc[r]);
    } else {
#pragma unroll
      for (int r = 0; r < 8; ++r) gsh[r][g] = sigm(acc[r]);
    }
    __syncthreads();
    // cell update: this thread owns cells (rA, j) and (rB, j)
    float iA = gsh[rA][j], fA = gsh[rA][128 + j], gA = gsh[rA][256 + j], oA = gsh[rA][384 + j];
    cA = fmaf(fA, cA, iA * gA);
    float hA = oA * tanh_fast(cA);
    float iB = gsh[rB][j], fB = gsh[rB][128 + j], gB = gsh[rB][256 + j], oB = gsh[rB][384 + j];
    cB = fmaf(fB, cB, iB * gB);
    float hB = oB * tanh_fast(cB);
    hs[rA][j] = hA;
    hs[rB][j] = hB;
    h1s[((size_t)(r0 + rA) * TT + t) * HH1 + j] = hA;
    h1s[((size_t)(r0 + rB) * TT + t) * HH1 + j] = hB;
    __syncthreads();
  }
}

// ---------------- rec2: layer-2 recurrence + fused dense head ----------------
__global__ __launch_bounds__(512) void k_rec2(const float* __restrict__ h1s,
                                              const float* __restrict__ ws,
                                              float* __restrict__ out) {
  __shared__ float h1sh[8][HH1];  // 4 KB
  __shared__ float h2sh[8][HH2];  // 2 KB
  __shared__ float gsh[8][GG2];   // 8 KB
  const float* W2T = ws + WS_W2T;
  const float* Wh2T = ws + WS_WH2T;
  const int r0 = blockIdx.x * 8;
  const int g = threadIdx.x & 255;     // gate column
  const int half = threadIdx.x >> 8;   // rows half*4 .. half*4+3
  const int crr = threadIdx.x >> 6;    // cell row 0..7
  const int cj = threadIdx.x & 63;     // cell col
  float c2 = 0.f;
  h2sh[crr][cj] = 0.f;
  __syncthreads();
  const bool isg = (g >= 128) && (g < 192);
  const float bias = ws[WS_B2 + g];

  for (int t = 0; t < TT; ++t) {
    // stage h1 tile (8 x 128)
#pragma unroll
    for (int p = 0; p < 2; ++p) {
      int ii = threadIdx.x + p * 512;
      int r = ii >> 7, k = ii & 127;
      h1sh[r][k] = h1s[((size_t)(r0 + r) * TT + t) * HH1 + k];
    }
    __syncthreads();

    float acc[4];
#pragma unroll
    for (int r = 0; r < 4; ++r) acc[r] = bias;
    for (int k = 0; k < HH1; k += 4) {
      float w0 = W2T[(k + 0) * GG2 + g];
      float w1 = W2T[(k + 1) * GG2 + g];
      float w2 = W2T[(k + 2) * GG2 + g];
      float w3 = W2T[(k + 3) * GG2 + g];
#pragma unroll
      for (int r = 0; r < 4; ++r) {
        float4 hv = *(const float4*)&h1sh[half * 4 + r][k];
        acc[r] = fmaf(hv.x, w0, acc[r]);
        acc[r] = fmaf(hv.y, w1, acc[r]);
        acc[r] = fmaf(hv.z, w2, acc[r]);
        acc[r] = fmaf(hv.w, w3, acc[r]);
      }
    }
    for (int k = 0; k < HH2; k += 4) {
      float w0 = Wh2T[(k + 0) * GG2 + g];
      float w1 = Wh2T[(k + 1) * GG2 + g];
      float w2 = Wh2T[(k + 2) * GG2 + g];
      float w3 = Wh2T[(k + 3) * GG2 + g];
#pragma unroll
      for (int r = 0; r < 4; ++r) {
        float4 hv = *(const float4*)&h2sh[half * 4 + r][k];
        acc[r] = fmaf(hv.x, w0, acc[r]);
        acc[r] = fmaf(hv.y, w1, acc[r]);
        acc[r] = fmaf(hv.z, w2, acc[r]);
        acc[r] = fmaf(hv.w, w3, acc[r]);
      }
    }
    if (isg) {
#pragma unroll
      for (int r = 0; r < 4; ++r) gsh[half * 4 + r][g] = tanh_fast(acc[r]);
    } else {
#pragma unroll
      for (int r = 0; r < 4; ++r) gsh[half * 4 + r][g] = sigm(acc[r]);
    }
    __syncthreads();
    float ii = gsh[crr][cj], ff = gsh[crr][64 + cj], gg = gsh[crr][128 + cj], oo = gsh[crr][192 + cj];
    c2 = fmaf(ff, c2, ii * gg);
    float h = oo * tanh_fast(c2);
    h2sh[crr][cj] = h;
    __syncthreads();
  }

  // dense head on final h2: out[r][o] = relu(sum_k h2[r][k] * WdT[k][o] + bd[o])
  const float* WdT = ws + WS_WDT;
  float acc = ws[WS_BD + cj];
  for (int k = 0; k < HH2; ++k)
    acc = fmaf(h2sh[crr][k], WdT[k * OO + cj], acc);
  out[(size_t)(r0 + crr) * OO + cj] = fmaxf(acc, 0.f);
}

extern "C" void kernel_launch(void* const* d_in, const int* in_sizes, int n_in,
                              void* d_out, int out_size, void* d_ws, size_t ws_size,
                              hipStream_t stream) {
  const float* x       = (const float*)d_in[0];
  const float* w_ih1   = (const float*)d_in[1];
  const float* w_hh1   = (const float*)d_in[2];
  const float* b_ih1   = (const float*)d_in[3];
  const float* b_hh1   = (const float*)d_in[4];
  const float* w_ih2   = (const float*)d_in[5];
  const float* w_hh2   = (const float*)d_in[6];
  const float* b_ih2   = (const float*)d_in[7];
  const float* b_hh2   = (const float*)d_in[8];
  const float* w_dense = (const float*)d_in[9];
  const float* b_dense = (const float*)d_in[10];
  float* ws = (float*)d_ws;
  float* h1s = ws + WS_H1S;
  __hip_bfloat16* xg1 = (__hip_bfloat16*)(ws + WS_XG1);
  float* out = (float*)d_out;

  hipLaunchKernelGGL(k_prep, dim3(256), dim3(256), 0, stream,
                     w_ih1, w_hh1, b_ih1, b_hh1, w_ih2, w_hh2, b_ih2, b_hh2,
                     w_dense, b_dense, ws);
  hipLaunchKernelGGL(k_gemm1, dim3((BB * TT) / MT1), dim3(512), 0, stream, x, ws, xg1);
  hipLaunchKernelGGL(k_rec1, dim3(BB / 8), dim3(512), 0, stream, xg1, ws, h1s);
  hipLaunchKernelGGL(k_rec2, dim3(BB / 8), dim3(512), 0, stream, h1s, ws, out);
}

// Round 3
// 1062.134 us; speedup vs baseline: 2.5966x; 2.5966x over previous
//
#include <hip/hip_runtime.h>
#include <hip/hip_bf16.h>

#define BB  2048
#define TT  128
#define DD  128
#define HH1 128
#define GG1 512
#define HH2 64
#define GG2 256
#define OO  64

typedef __attribute__((ext_vector_type(8))) short  short8;
typedef __attribute__((ext_vector_type(4))) float  floatx4;

// ws byte offsets
#define OFF_WHH1 0            // bf16 [512][128]  (orig layout, bf16)
#define OFF_WIH1 131072       // bf16 [512][128]
#define OFF_WIH2 262144       // bf16 [256][128]
#define OFF_WHH2 327680       // bf16 [256][64]
#define OFF_B1   360448       // f32 [512]  b_ih1+b_hh1
#define OFF_B2   362496       // f32 [256]  b_ih2+b_hh2
#define OFF_H1S  524288       // bf16 [2048*128][128]  layer-1 hidden seq
#define OFF_XG1  67633152     // bf16 [2048*128][512]  xg1
#define OFF_XG2  OFF_XG1      // xg2 [2048*128][256] reuses xg1 region (xg1 dead after rec1)
// total ~336 MB (< 391 MB proven in round 1)

__device__ __forceinline__ short f2bf(float f) {
  unsigned u = __float_as_uint(f);
  unsigned r = (u + 0x7FFFu + ((u >> 16) & 1u)) >> 16;
  return (short)r;
}
__device__ __forceinline__ float bf2f(unsigned short s) {
  return __uint_as_float(((unsigned)s) << 16);
}
__device__ __forceinline__ float sigm(float x) { return 1.0f / (1.0f + __expf(-x)); }
__device__ __forceinline__ float tanh_fast(float x) { return 1.0f - 2.0f / (1.0f + __expf(2.0f * x)); }

// ---------------- prep: bf16 weight conversion + combined biases ----------------
__global__ void k_prep(const float* __restrict__ wih1, const float* __restrict__ whh1,
                       const float* __restrict__ bih1, const float* __restrict__ bhh1,
                       const float* __restrict__ wih2, const float* __restrict__ whh2,
                       const float* __restrict__ bih2, const float* __restrict__ bhh2,
                       char* __restrict__ ws) {
  short* WHH1 = (short*)(ws + OFF_WHH1);
  short* WIH1 = (short*)(ws + OFF_WIH1);
  short* WIH2 = (short*)(ws + OFF_WIH2);
  short* WHH2 = (short*)(ws + OFF_WHH2);
  float* B1 = (float*)(ws + OFF_B1);
  float* B2 = (float*)(ws + OFF_B2);
  int idx = blockIdx.x * blockDim.x + threadIdx.x;
  int stride = gridDim.x * blockDim.x;
  for (int i = idx; i < GG1 * DD; i += stride) { WIH1[i] = f2bf(wih1[i]); WHH1[i] = f2bf(whh1[i]); }
  for (int i = idx; i < GG2 * HH1; i += stride) WIH2[i] = f2bf(wih2[i]);
  for (int i = idx; i < GG2 * HH2; i += stride) WHH2[i] = f2bf(whh2[i]);
  for (int i = idx; i < GG1; i += stride) B1[i] = bih1[i] + bhh1[i];
  for (int i = idx; i < GG2; i += stride) B2[i] = bih2[i] + bhh2[i];
}

// ---------------- gemm1: xg1[m][g] = bf16( x[m][:]·W_ih1[g][:] + B1[g] ) ----------------
// grid 8192 x 256thr; block: 32 rows x 512 cols; wave: 32 rows x 128 cols
__global__ __launch_bounds__(256) void k_gemm1(const float* __restrict__ x,
                                               const char* __restrict__ ws,
                                               short* __restrict__ xg1) {
  const short* W = (const short*)(ws + OFF_WIH1);
  const float* B1 = (const float*)(ws + OFF_B1);
  const int lane = threadIdx.x & 63;
  const int wv = threadIdx.x >> 6;
  const int col = lane & 15, quad = lane >> 4;
  const int n0 = wv * 128;
  const size_t m0 = (size_t)blockIdx.x * 32;

  floatx4 acc[2][8];
#pragma unroll
  for (int nt = 0; nt < 8; ++nt) {
    float b = B1[n0 + nt * 16 + col];
#pragma unroll
    for (int mt = 0; mt < 2; ++mt) acc[mt][nt] = (floatx4){b, b, b, b};
  }
#pragma unroll
  for (int kk = 0; kk < 4; ++kk) {
    const int k0 = kk * 32 + quad * 8;
    short8 a[2];
#pragma unroll
    for (int mt = 0; mt < 2; ++mt) {
      const float* xp = x + (m0 + mt * 16 + col) * DD + k0;
      float4 v0 = *(const float4*)xp;
      float4 v1 = *(const float4*)(xp + 4);
      short8 tmp;
      tmp[0] = f2bf(v0.x); tmp[1] = f2bf(v0.y); tmp[2] = f2bf(v0.z); tmp[3] = f2bf(v0.w);
      tmp[4] = f2bf(v1.x); tmp[5] = f2bf(v1.y); tmp[6] = f2bf(v1.z); tmp[7] = f2bf(v1.w);
      a[mt] = tmp;
    }
#pragma unroll
    for (int nt = 0; nt < 8; ++nt) {
      short8 bfr = *(const short8*)&W[(n0 + nt * 16 + col) * DD + k0];
      acc[0][nt] = __builtin_amdgcn_mfma_f32_16x16x32_bf16(a[0], bfr, acc[0][nt], 0, 0, 0);
      acc[1][nt] = __builtin_amdgcn_mfma_f32_16x16x32_bf16(a[1], bfr, acc[1][nt], 0, 0, 0);
    }
  }
#pragma unroll
  for (int mt = 0; mt < 2; ++mt)
#pragma unroll
    for (int nt = 0; nt < 8; ++nt)
#pragma unroll
      for (int r = 0; r < 4; ++r)
        xg1[(m0 + mt * 16 + quad * 4 + r) * GG1 + n0 + nt * 16 + col] = f2bf(acc[mt][nt][r]);
}

// ---------------- rec1: layer-1 recurrence (MFMA), 8 real rows/block (M=16 padded) ----------------
// grid 256 x 512thr (8 waves); wave: 64 gate cols (4 n-tiles); Whh in registers
__global__ __launch_bounds__(512) void k_rec1(const short* __restrict__ xg1,
                                              const char* __restrict__ ws,
                                              short* __restrict__ h1s) {
  __shared__ short hbuf[16 * 136];   // bf16 h, stride 136 (2-way-bank only), rows 8..15 stay 0
  __shared__ float gsm[8 * GG1];     // activated gates fp32
  const short* WHH = (const short*)(ws + OFF_WHH1);
  const int lane = threadIdx.x & 63;
  const int wv = threadIdx.x >> 6;         // 0..7
  const int col = lane & 15, quad = lane >> 4;
  const int n0 = wv * 64;
  const int r0 = blockIdx.x * 8;
  const bool isg = (wv == 4 || wv == 5);

  short8 wf[4][4];                   // [n-tile][k-step] weight fragments, resident
#pragma unroll
  for (int nt = 0; nt < 4; ++nt)
#pragma unroll
    for (int kk = 0; kk < 4; ++kk)
      wf[nt][kk] = *(const short8*)&WHH[(n0 + nt * 16 + col) * HH1 + kk * 32 + quad * 8];

  for (int i = threadIdx.x; i < 16 * 136; i += 512) hbuf[i] = 0;

  unsigned short cur[16], nxt[16];
#pragma unroll
  for (int i = 0; i < 16; ++i) { cur[i] = 0; nxt[i] = 0; }
  if (quad < 2) {
    const short* xp = &xg1[((size_t)(r0 + quad * 4) * TT) * GG1 + n0 + col];
#pragma unroll
    for (int nt = 0; nt < 4; ++nt)
#pragma unroll
      for (int r = 0; r < 4; ++r)
        cur[nt * 4 + r] = (unsigned short)xp[(size_t)r * TT * GG1 + nt * 16];
  }

  const int j = threadIdx.x & 127;   // cell col
  const int rr = threadIdx.x >> 7;   // cell rows rr, rr+4
  float cA = 0.f, cB = 0.f;
  __syncthreads();

  for (int t = 0; t < TT; ++t) {
    floatx4 acc[4];
#pragma unroll
    for (int nt = 0; nt < 4; ++nt)
      acc[nt] = (floatx4){bf2f(cur[nt * 4 + 0]), bf2f(cur[nt * 4 + 1]),
                          bf2f(cur[nt * 4 + 2]), bf2f(cur[nt * 4 + 3])};
    short8 a[4];
#pragma unroll
    for (int kk = 0; kk < 4; ++kk)
      a[kk] = *(const short8*)&hbuf[col * 136 + kk * 32 + quad * 8];

    if (t + 1 < TT && quad < 2) {    // prefetch next preact
      const short* xp = &xg1[(((size_t)(r0 + quad * 4)) * TT + (t + 1)) * GG1 + n0 + col];
#pragma unroll
      for (int nt = 0; nt < 4; ++nt)
#pragma unroll
        for (int r = 0; r < 4; ++r)
          nxt[nt * 4 + r] = (unsigned short)xp[(size_t)r * TT * GG1 + nt * 16];
    }
#pragma unroll
    for (int kk = 0; kk < 4; ++kk)
#pragma unroll
      for (int nt = 0; nt < 4; ++nt)
        acc[nt] = __builtin_amdgcn_mfma_f32_16x16x32_bf16(a[kk], wf[nt][kk], acc[nt], 0, 0, 0);

    if (quad < 2) {
#pragma unroll
      for (int nt = 0; nt < 4; ++nt)
#pragma unroll
        for (int r = 0; r < 4; ++r) {
          float v = acc[nt][r];
          gsm[(quad * 4 + r) * GG1 + n0 + nt * 16 + col] = isg ? tanh_fast(v) : sigm(v);
        }
    }
    __syncthreads();

    {
      float i0 = gsm[rr * GG1 + j],       f0 = gsm[rr * GG1 + 128 + j];
      float g0 = gsm[rr * GG1 + 256 + j], o0 = gsm[rr * GG1 + 384 + j];
      cA = fmaf(f0, cA, i0 * g0);
      float hA = o0 * tanh_fast(cA);
      int r2 = rr + 4;
      float i1 = gsm[r2 * GG1 + j],       f1 = gsm[r2 * GG1 + 128 + j];
      float g1 = gsm[r2 * GG1 + 256 + j], o1 = gsm[r2 * GG1 + 384 + j];
      cB = fmaf(f1, cB, i1 * g1);
      float hB = o1 * tanh_fast(cB);
      short ha = f2bf(hA), hb = f2bf(hB);
      hbuf[rr * 136 + j] = ha;
      hbuf[r2 * 136 + j] = hb;
      h1s[((size_t)(r0 + rr) * TT + t) * HH1 + j] = ha;
      h1s[((size_t)(r0 + r2) * TT + t) * HH1 + j] = hb;
    }
    __syncthreads();
#pragma unroll
    for (int i = 0; i < 16; ++i) cur[i] = nxt[i];
  }
}

// ---------------- gemm2: xg2[m][g] = bf16( h1s[m][:]·W_ih2[g][:] + B2[g] ) ----------------
// grid 8192 x 256thr; block: 32 rows x 256 cols; wave: 32 rows x 64 cols
__global__ __launch_bounds__(256) void k_gemm2(const char* __restrict__ ws,
                                               short* __restrict__ xg2) {
  const short* H = (const short*)(ws + OFF_H1S);
  const short* W = (const short*)(ws + OFF_WIH2);
  const float* B2 = (const float*)(ws + OFF_B2);
  const int lane = threadIdx.x & 63;
  const int wv = threadIdx.x >> 6;
  const int col = lane & 15, quad = lane >> 4;
  const int n0 = wv * 64;
  const size_t m0 = (size_t)blockIdx.x * 32;

  floatx4 acc[2][4];
#pragma unroll
  for (int nt = 0; nt < 4; ++nt) {
    float b = B2[n0 + nt * 16 + col];
#pragma unroll
    for (int mt = 0; mt < 2; ++mt) acc[mt][nt] = (floatx4){b, b, b, b};
  }
#pragma unroll
  for (int kk = 0; kk < 4; ++kk) {
    const int k0 = kk * 32 + quad * 8;
    short8 a[2];
#pragma unroll
    for (int mt = 0; mt < 2; ++mt)
      a[mt] = *(const short8*)&H[(m0 + mt * 16 + col) * HH1 + k0];
#pragma unroll
    for (int nt = 0; nt < 4; ++nt) {
      short8 bfr = *(const short8*)&W[(n0 + nt * 16 + col) * HH1 + k0];
      acc[0][nt] = __builtin_amdgcn_mfma_f32_16x16x32_bf16(a[0], bfr, acc[0][nt], 0, 0, 0);
      acc[1][nt] = __builtin_amdgcn_mfma_f32_16x16x32_bf16(a[1], bfr, acc[1][nt], 0, 0, 0);
    }
  }
#pragma unroll
  for (int mt = 0; mt < 2; ++mt)
#pragma unroll
    for (int nt = 0; nt < 4; ++nt)
#pragma unroll
      for (int r = 0; r < 4; ++r)
        xg2[(m0 + mt * 16 + quad * 4 + r) * GG2 + n0 + nt * 16 + col] = f2bf(acc[mt][nt][r]);
}

// ---------------- rec2: layer-2 recurrence (MFMA) + fused dense head ----------------
// grid 256 x 256thr (4 waves); wave: 64 gate cols (4 n-tiles); K=64 (2 k-steps)
__global__ __launch_bounds__(256) void k_rec2(const char* __restrict__ ws,
                                              const short* __restrict__ xg2,
                                              const float* __restrict__ wd,
                                              const float* __restrict__ bd,
                                              float* __restrict__ out) {
  __shared__ short hbuf[16 * 72];    // bf16 h2, stride 72
  __shared__ float gsm[8 * GG2];
  __shared__ float h2f[8 * HH2];     // final fp32 h2 for dense head
  const short* WHH = (const short*)(ws + OFF_WHH2);
  const int lane = threadIdx.x & 63;
  const int wv = threadIdx.x >> 6;   // 0..3
  const int col = lane & 15, quad = lane >> 4;
  const int n0 = wv * 64;
  const int r0 = blockIdx.x * 8;
  const bool isg = (wv == 2);

  short8 wf[4][2];
#pragma unroll
  for (int nt = 0; nt < 4; ++nt)
#pragma unroll
    for (int kk = 0; kk < 2; ++kk)
      wf[nt][kk] = *(const short8*)&WHH[(n0 + nt * 16 + col) * HH2 + kk * 32 + quad * 8];

  for (int i = threadIdx.x; i < 16 * 72; i += 256) hbuf[i] = 0;

  unsigned short cur[16], nxt[16];
#pragma unroll
  for (int i = 0; i < 16; ++i) { cur[i] = 0; nxt[i] = 0; }
  if (quad < 2) {
    const short* xp = &xg2[((size_t)(r0 + quad * 4) * TT) * GG2 + n0 + col];
#pragma unroll
    for (int nt = 0; nt < 4; ++nt)
#pragma unroll
      for (int r = 0; r < 4; ++r)
        cur[nt * 4 + r] = (unsigned short)xp[(size_t)r * TT * GG2 + nt * 16];
  }

  const int j = threadIdx.x & 63;
  const int rr = threadIdx.x >> 6;   // 0..3 ; rows rr, rr+4
  float cA = 0.f, cB = 0.f;
  __syncthreads();

  for (int t = 0; t < TT; ++t) {
    floatx4 acc[4];
#pragma unroll
    for (int nt = 0; nt < 4; ++nt)
      acc[nt] = (floatx4){bf2f(cur[nt * 4 + 0]), bf2f(cur[nt * 4 + 1]),
                          bf2f(cur[nt * 4 + 2]), bf2f(cur[nt * 4 + 3])};
    short8 a[2];
#pragma unroll
    for (int kk = 0; kk < 2; ++kk)
      a[kk] = *(const short8*)&hbuf[col * 72 + kk * 32 + quad * 8];

    if (t + 1 < TT && quad < 2) {
      const short* xp = &xg2[(((size_t)(r0 + quad * 4)) * TT + (t + 1)) * GG2 + n0 + col];
#pragma unroll
      for (int nt = 0; nt < 4; ++nt)
#pragma unroll
        for (int r = 0; r < 4; ++r)
          nxt[nt * 4 + r] = (unsigned short)xp[(size_t)r * TT * GG2 + nt * 16];
    }
#pragma unroll
    for (int kk = 0; kk < 2; ++kk)
#pragma unroll
      for (int nt = 0; nt < 4; ++nt)
        acc[nt] = __builtin_amdgcn_mfma_f32_16x16x32_bf16(a[kk], wf[nt][kk], acc[nt], 0, 0, 0);

    if (quad < 2) {
#pragma unroll
      for (int nt = 0; nt < 4; ++nt)
#pragma unroll
        for (int r = 0; r < 4; ++r) {
          float v = acc[nt][r];
          gsm[(quad * 4 + r) * GG2 + n0 + nt * 16 + col] = isg ? tanh_fast(v) : sigm(v);
        }
    }
    __syncthreads();

    {
      float i0 = gsm[rr * GG2 + j],      f0 = gsm[rr * GG2 + 64 + j];
      float g0 = gsm[rr * GG2 + 128 + j], o0 = gsm[rr * GG2 + 192 + j];
      cA = fmaf(f0, cA, i0 * g0);
      float hA = o0 * tanh_fast(cA);
      int r2 = rr + 4;
      float i1 = gsm[r2 * GG2 + j],      f1 = gsm[r2 * GG2 + 64 + j];
      float g1 = gsm[r2 * GG2 + 128 + j], o1 = gsm[r2 * GG2 + 192 + j];
      cB = fmaf(f1, cB, i1 * g1);
      float hB = o1 * tanh_fast(cB);
      hbuf[rr * 72 + j] = f2bf(hA);
      hbuf[r2 * 72 + j] = f2bf(hB);
      if (t == TT - 1) { h2f[rr * HH2 + j] = hA; h2f[r2 * HH2 + j] = hB; }
    }
    __syncthreads();
#pragma unroll
    for (int i = 0; i < 16; ++i) cur[i] = nxt[i];
  }

  // dense head (fp32): out[r][o] = relu( h2[r][:]·wd[o][:] + bd[o] )
  {
    const int o = threadIdx.x & 63;
    const int rh = threadIdx.x >> 6;
    for (int r = rh; r < 8; r += 4) {
      float acc = bd[o];
      for (int k = 0; k < HH2; ++k)
        acc = fmaf(h2f[r * HH2 + k], wd[o * HH2 + k], acc);
      out[(size_t)(r0 + r) * OO + o] = fmaxf(acc, 0.f);
    }
  }
}

extern "C" void kernel_launch(void* const* d_in, const int* in_sizes, int n_in,
                              void* d_out, int out_size, void* d_ws, size_t ws_size,
                              hipStream_t stream) {
  const float* x       = (const float*)d_in[0];
  const float* w_ih1   = (const float*)d_in[1];
  const float* w_hh1   = (const float*)d_in[2];
  const float* b_ih1   = (const float*)d_in[3];
  const float* b_hh1   = (const float*)d_in[4];
  const float* w_ih2   = (const float*)d_in[5];
  const float* w_hh2   = (const float*)d_in[6];
  const float* b_ih2   = (const float*)d_in[7];
  const float* b_hh2   = (const float*)d_in[8];
  const float* w_dense = (const float*)d_in[9];
  const float* b_dense = (const float*)d_in[10];
  char* ws = (char*)d_ws;
  short* xg1 = (short*)(ws + OFF_XG1);
  short* xg2 = (short*)(ws + OFF_XG2);
  float* out = (float*)d_out;

  hipLaunchKernelGGL(k_prep, dim3(256), dim3(256), 0, stream,
                     w_ih1, w_hh1, b_ih1, b_hh1, w_ih2, w_hh2, b_ih2, b_hh2, ws);
  hipLaunchKernelGGL(k_gemm1, dim3((BB * TT) / 32), dim3(256), 0, stream, x, ws, xg1);
  hipLaunchKernelGGL(k_rec1, dim3(BB / 8), dim3(512), 0, stream, xg1, ws,
                     (short*)(ws + OFF_H1S));
  hipLaunchKernelGGL(k_gemm2, dim3((BB * TT) / 32), dim3(256), 0, stream, ws, xg2);
  hipLaunchKernelGGL(k_rec2, dim3(BB / 8), dim3(256), 0, stream, ws, xg2, w_dense, b_dense, out);
}

// Round 4
// 579.768 us; speedup vs baseline: 4.7570x; 1.8320x over previous
//
#include <hip/hip_runtime.h>
#include <hip/hip_bf16.h>

#define BB  2048
#define TT  128
#define DD  128
#define HH1 128
#define GG1 512
#define HH2 64
#define GG2 256
#define OO  64

typedef __attribute__((ext_vector_type(8))) short  short8;
typedef __attribute__((ext_vector_type(4))) float  floatx4;

// ws byte offsets
#define OFF_WHH1 0            // bf16 [512][128]
#define OFF_WIH1 131072       // bf16 [512][128]
#define OFF_WIH2 262144       // bf16 [256][128]
#define OFF_WHH2 327680       // bf16 [256][64]
#define OFF_B1   360448       // f32 [512]  b_ih1+b_hh1
#define OFF_B2   362496       // f32 [256]  b_ih2+b_hh2
#define OFF_XBF  524288       // bf16 [2048][128][128]  x cast to bf16
#define OFF_H1S  67633152     // bf16 [2048][128][128]  layer-1 hidden seq
// total ~135 MB

__device__ __forceinline__ short f2bf(float f) {
  unsigned u = __float_as_uint(f);
  unsigned r = (u + 0x7FFFu + ((u >> 16) & 1u)) >> 16;
  return (short)r;
}
__device__ __forceinline__ float sigm(float x) { return 1.0f / (1.0f + __expf(-x)); }
__device__ __forceinline__ float tanh_fast(float x) { return 1.0f - 2.0f / (1.0f + __expf(2.0f * x)); }

// ---------------- prep: bf16 weight conversion + combined biases ----------------
__global__ void k_prep(const float* __restrict__ wih1, const float* __restrict__ whh1,
                       const float* __restrict__ bih1, const float* __restrict__ bhh1,
                       const float* __restrict__ wih2, const float* __restrict__ whh2,
                       const float* __restrict__ bih2, const float* __restrict__ bhh2,
                       char* __restrict__ ws) {
  short* WHH1 = (short*)(ws + OFF_WHH1);
  short* WIH1 = (short*)(ws + OFF_WIH1);
  short* WIH2 = (short*)(ws + OFF_WIH2);
  short* WHH2 = (short*)(ws + OFF_WHH2);
  float* B1 = (float*)(ws + OFF_B1);
  float* B2 = (float*)(ws + OFF_B2);
  int idx = blockIdx.x * blockDim.x + threadIdx.x;
  int stride = gridDim.x * blockDim.x;
  for (int i = idx; i < GG1 * DD; i += stride) { WIH1[i] = f2bf(wih1[i]); WHH1[i] = f2bf(whh1[i]); }
  for (int i = idx; i < GG2 * HH1; i += stride) WIH2[i] = f2bf(wih2[i]);
  for (int i = idx; i < GG2 * HH2; i += stride) WHH2[i] = f2bf(whh2[i]);
  for (int i = idx; i < GG1; i += stride) B1[i] = bih1[i] + bhh1[i];
  for (int i = idx; i < GG2; i += stride) B2[i] = bih2[i] + bhh2[i];
}

// ---------------- xcast: x fp32 -> bf16, 8 elems/thread ----------------
__global__ __launch_bounds__(256) void k_xcast(const float* __restrict__ x,
                                               short* __restrict__ xbf) {
  size_t i = ((size_t)blockIdx.x * 256 + threadIdx.x) * 8;
  float4 a = *(const float4*)&x[i];
  float4 b = *(const float4*)&x[i + 4];
  short8 o;
  o[0] = f2bf(a.x); o[1] = f2bf(a.y); o[2] = f2bf(a.z); o[3] = f2bf(a.w);
  o[4] = f2bf(b.x); o[5] = f2bf(b.y); o[6] = f2bf(b.z); o[7] = f2bf(b.w);
  *(short8*)&xbf[i] = o;
}

// ---------------- rec1f: fused input-proj + recurrence, layer 1 ----------------
// grid 256 x 512thr (8 waves); wave: 64 gate cols (4 n-tiles); W_ih+W_hh in registers
__global__ __launch_bounds__(512, 2) void k_rec1f(const char* __restrict__ ws,
                                                  short* __restrict__ h1s) {
  __shared__ short hbuf[16 * 136];    // bf16 h, rows 8..15 stay 0
  __shared__ float gsm[8 * 516];      // raw preacts, padded stride
  const short* WHH = (const short*)(ws + OFF_WHH1);
  const short* WIH = (const short*)(ws + OFF_WIH1);
  const short* XBF = (const short*)(ws + OFF_XBF);
  const float* B1 = (const float*)(ws + OFF_B1);
  const int lane = threadIdx.x & 63;
  const int wv = threadIdx.x >> 6;          // 0..7
  const int col = lane & 15, quad = lane >> 4;
  const int n0 = wv * 64;
  const int r0 = blockIdx.x * 8;

  short8 wh[4][4], wx[4][4];
#pragma unroll
  for (int nt = 0; nt < 4; ++nt)
#pragma unroll
    for (int kk = 0; kk < 4; ++kk) {
      wh[nt][kk] = *(const short8*)&WHH[(n0 + nt * 16 + col) * HH1 + kk * 32 + quad * 8];
      wx[nt][kk] = *(const short8*)&WIH[(n0 + nt * 16 + col) * DD + kk * 32 + quad * 8];
    }
  float bias[4];
#pragma unroll
  for (int nt = 0; nt < 4; ++nt) bias[nt] = B1[n0 + nt * 16 + col];

  for (int i = threadIdx.x; i < 16 * 136; i += 512) hbuf[i] = 0;

  const bool aload = (col < 8);
  const short* xbase = XBF + (size_t)(r0 + (col & 7)) * TT * DD;
  short8 ax_cur[4], ax_nxt[4];
#pragma unroll
  for (int kk = 0; kk < 4; ++kk) {
    short8 z = {0, 0, 0, 0, 0, 0, 0, 0};
    ax_cur[kk] = aload ? *(const short8*)&xbase[kk * 32 + quad * 8] : z;
    ax_nxt[kk] = z;
  }

  const int j = threadIdx.x & 127;
  const int rr = threadIdx.x >> 7;    // rows rr, rr+4
  float cA = 0.f, cB = 0.f;
  __syncthreads();

  for (int t = 0; t < TT; ++t) {
    if (t + 1 < TT && aload) {
#pragma unroll
      for (int kk = 0; kk < 4; ++kk)
        ax_nxt[kk] = *(const short8*)&xbase[(t + 1) * DD + kk * 32 + quad * 8];
    }
    floatx4 acc[4];
#pragma unroll
    for (int nt = 0; nt < 4; ++nt)
      acc[nt] = (floatx4){bias[nt], bias[nt], bias[nt], bias[nt]};
    // input projection (h-independent)
#pragma unroll
    for (int kk = 0; kk < 4; ++kk)
#pragma unroll
      for (int nt = 0; nt < 4; ++nt)
        acc[nt] = __builtin_amdgcn_mfma_f32_16x16x32_bf16(ax_cur[kk], wx[nt][kk], acc[nt], 0, 0, 0);
    // recurrence
    short8 ah[4];
#pragma unroll
    for (int kk = 0; kk < 4; ++kk)
      ah[kk] = *(const short8*)&hbuf[col * 136 + kk * 32 + quad * 8];
#pragma unroll
    for (int kk = 0; kk < 4; ++kk)
#pragma unroll
      for (int nt = 0; nt < 4; ++nt)
        acc[nt] = __builtin_amdgcn_mfma_f32_16x16x32_bf16(ah[kk], wh[nt][kk], acc[nt], 0, 0, 0);

    if (quad < 2) {
#pragma unroll
      for (int nt = 0; nt < 4; ++nt)
#pragma unroll
        for (int r = 0; r < 4; ++r)
          gsm[(quad * 4 + r) * 516 + n0 + nt * 16 + col] = acc[nt][r];
    }
    __syncthreads();

    {
      float i0 = gsm[rr * 516 + j],       f0 = gsm[rr * 516 + 128 + j];
      float g0 = gsm[rr * 516 + 256 + j], o0 = gsm[rr * 516 + 384 + j];
      cA = fmaf(sigm(f0), cA, sigm(i0) * tanh_fast(g0));
      float hA = sigm(o0) * tanh_fast(cA);
      int r2 = rr + 4;
      float i1 = gsm[r2 * 516 + j],       f1 = gsm[r2 * 516 + 128 + j];
      float g1 = gsm[r2 * 516 + 256 + j], o1 = gsm[r2 * 516 + 384 + j];
      cB = fmaf(sigm(f1), cB, sigm(i1) * tanh_fast(g1));
      float hB = sigm(o1) * tanh_fast(cB);
      short ha = f2bf(hA), hb = f2bf(hB);
      hbuf[rr * 136 + j] = ha;
      hbuf[r2 * 136 + j] = hb;
      h1s[((size_t)(r0 + rr) * TT + t) * HH1 + j] = ha;
      h1s[((size_t)(r0 + r2) * TT + t) * HH1 + j] = hb;
    }
    __syncthreads();
#pragma unroll
    for (int kk = 0; kk < 4; ++kk) ax_cur[kk] = ax_nxt[kk];
  }
}

// ---------------- rec2f: fused input-proj + recurrence, layer 2 + dense head ----------------
// grid 256 x 256thr (4 waves); wave: 64 gate cols (4 n-tiles)
__global__ __launch_bounds__(256) void k_rec2f(const char* __restrict__ ws,
                                               const short* __restrict__ h1s,
                                               const float* __restrict__ wd,
                                               const float* __restrict__ bd,
                                               float* __restrict__ out) {
  __shared__ short hbuf[16 * 72];     // bf16 h2, rows 8..15 stay 0
  __shared__ float gsm[8 * 260];      // raw preacts, padded
  __shared__ float h2f[8 * HH2];      // final fp32 h2
  const short* WHH = (const short*)(ws + OFF_WHH2);
  const short* WIH = (const short*)(ws + OFF_WIH2);
  const float* B2 = (const float*)(ws + OFF_B2);
  const int lane = threadIdx.x & 63;
  const int wv = threadIdx.x >> 6;    // 0..3
  const int col = lane & 15, quad = lane >> 4;
  const int n0 = wv * 64;
  const int r0 = blockIdx.x * 8;

  short8 wh[4][2], wx[4][4];
#pragma unroll
  for (int nt = 0; nt < 4; ++nt) {
#pragma unroll
    for (int kk = 0; kk < 2; ++kk)
      wh[nt][kk] = *(const short8*)&WHH[(n0 + nt * 16 + col) * HH2 + kk * 32 + quad * 8];
#pragma unroll
    for (int kk = 0; kk < 4; ++kk)
      wx[nt][kk] = *(const short8*)&WIH[(n0 + nt * 16 + col) * HH1 + kk * 32 + quad * 8];
  }
  float bias[4];
#pragma unroll
  for (int nt = 0; nt < 4; ++nt) bias[nt] = B2[n0 + nt * 16 + col];

  for (int i = threadIdx.x; i < 16 * 72; i += 256) hbuf[i] = 0;

  const bool aload = (col < 8);
  const short* h1base = h1s + (size_t)(r0 + (col & 7)) * TT * HH1;
  short8 ax_cur[4], ax_nxt[4];
#pragma unroll
  for (int kk = 0; kk < 4; ++kk) {
    short8 z = {0, 0, 0, 0, 0, 0, 0, 0};
    ax_cur[kk] = aload ? *(const short8*)&h1base[kk * 32 + quad * 8] : z;
    ax_nxt[kk] = z;
  }

  const int j = threadIdx.x & 63;
  const int rr = threadIdx.x >> 6;    // rows rr, rr+4
  float cA = 0.f, cB = 0.f;
  __syncthreads();

  for (int t = 0; t < TT; ++t) {
    if (t + 1 < TT && aload) {
#pragma unroll
      for (int kk = 0; kk < 4; ++kk)
        ax_nxt[kk] = *(const short8*)&h1base[(t + 1) * HH1 + kk * 32 + quad * 8];
    }
    floatx4 acc[4];
#pragma unroll
    for (int nt = 0; nt < 4; ++nt)
      acc[nt] = (floatx4){bias[nt], bias[nt], bias[nt], bias[nt]};
#pragma unroll
    for (int kk = 0; kk < 4; ++kk)
#pragma unroll
      for (int nt = 0; nt < 4; ++nt)
        acc[nt] = __builtin_amdgcn_mfma_f32_16x16x32_bf16(ax_cur[kk], wx[nt][kk], acc[nt], 0, 0, 0);
    short8 ah[2];
#pragma unroll
    for (int kk = 0; kk < 2; ++kk)
      ah[kk] = *(const short8*)&hbuf[col * 72 + kk * 32 + quad * 8];
#pragma unroll
    for (int kk = 0; kk < 2; ++kk)
#pragma unroll
      for (int nt = 0; nt < 4; ++nt)
        acc[nt] = __builtin_amdgcn_mfma_f32_16x16x32_bf16(ah[kk], wh[nt][kk], acc[nt], 0, 0, 0);

    if (quad < 2) {
#pragma unroll
      for (int nt = 0; nt < 4; ++nt)
#pragma unroll
        for (int r = 0; r < 4; ++r)
          gsm[(quad * 4 + r) * 260 + n0 + nt * 16 + col] = acc[nt][r];
    }
    __syncthreads();

    {
      float i0 = gsm[rr * 260 + j],      f0 = gsm[rr * 260 + 64 + j];
      float g0 = gsm[rr * 260 + 128 + j], o0 = gsm[rr * 260 + 192 + j];
      cA = fmaf(sigm(f0), cA, sigm(i0) * tanh_fast(g0));
      float hA = sigm(o0) * tanh_fast(cA);
      int r2 = rr + 4;
      float i1 = gsm[r2 * 260 + j],      f1 = gsm[r2 * 260 + 64 + j];
      float g1 = gsm[r2 * 260 + 128 + j], o1 = gsm[r2 * 260 + 192 + j];
      cB = fmaf(sigm(f1), cB, sigm(i1) * tanh_fast(g1));
      float hB = sigm(o1) * tanh_fast(cB);
      hbuf[rr * 72 + j] = f2bf(hA);
      hbuf[r2 * 72 + j] = f2bf(hB);
      if (t == TT - 1) { h2f[rr * HH2 + j] = hA; h2f[r2 * HH2 + j] = hB; }
    }
    __syncthreads();
#pragma unroll
    for (int kk = 0; kk < 4; ++kk) ax_cur[kk] = ax_nxt[kk];
  }

  // dense head (fp32)
  {
    const int o = threadIdx.x & 63;
    const int rh = threadIdx.x >> 6;
    for (int r = rh; r < 8; r += 4) {
      float acc = bd[o];
      for (int k = 0; k < HH2; ++k)
        acc = fmaf(h2f[r * HH2 + k], wd[o * HH2 + k], acc);
      out[(size_t)(r0 + r) * OO + o] = fmaxf(acc, 0.f);
    }
  }
}

extern "C" void kernel_launch(void* const* d_in, const int* in_sizes, int n_in,
                              void* d_out, int out_size, void* d_ws, size_t ws_size,
                              hipStream_t stream) {
  const float* x       = (const float*)d_in[0];
  const float* w_ih1   = (const float*)d_in[1];
  const float* w_hh1   = (const float*)d_in[2];
  const float* b_ih1   = (const float*)d_in[3];
  const float* b_hh1   = (const float*)d_in[4];
  const float* w_ih2   = (const float*)d_in[5];
  const float* w_hh2   = (const float*)d_in[6];
  const float* b_ih2   = (const float*)d_in[7];
  const float* b_hh2   = (const float*)d_in[8];
  const float* w_dense = (const float*)d_in[9];
  const float* b_dense = (const float*)d_in[10];
  char* ws = (char*)d_ws;
  short* xbf = (short*)(ws + OFF_XBF);
  short* h1s = (short*)(ws + OFF_H1S);
  float* out = (float*)d_out;

  hipLaunchKernelGGL(k_prep, dim3(256), dim3(256), 0, stream,
                     w_ih1, w_hh1, b_ih1, b_hh1, w_ih2, w_hh2, b_ih2, b_hh2, ws);
  hipLaunchKernelGGL(k_xcast, dim3((BB * TT * DD) / (256 * 8)), dim3(256), 0, stream, x, xbf);
  hipLaunchKernelGGL(k_rec1f, dim3(BB / 8), dim3(512), 0, stream, ws, h1s);
  hipLaunchKernelGGL(k_rec2f, dim3(BB / 8), dim3(256), 0, stream, ws, h1s, w_dense, b_dense, out);
}